// Round 1
// baseline (65.419 us; speedup 1.0000x reference)
//
#include <hip/hip_runtime.h>

// Vanilla tanh RNN scan: B=4096, T=1024, F=H=3.
// 4 lanes per batch (lane j = hidden unit j, lane 3 idle), DPP quad broadcasts
// for the recurrent h exchange. tanh(p) = 1 - 2*rcp(exp2(s*p)+1), s=2*log2(e)
// folded into weights. Recurrence carried on r = rcp(exp2(z)+1).

static constexpr int BATCH = 4096;
static constexpr int TLEN  = 1024;
static constexpr int HN_OFF = BATCH * TLEN * 3;  // 12582912

#define SCL 2.8853900817779268f  // 2*log2(e)

template<int K>
__device__ __forceinline__ float qbcast(float v) {
  // broadcast lane K of each quad to all 4 lanes (quad_perm [K,K,K,K])
  int r = __builtin_amdgcn_update_dpp(0, __float_as_int(v), K * 0x55, 0xF, 0xF, true);
  return __int_as_float(r);
}

// component access into a float4[12] chunk with compile-time index
#define XC(q) (((q)&3)==0 ? buf[(q)>>2].x : ((q)&3)==1 ? buf[(q)>>2].y : \
               ((q)&3)==2 ? buf[(q)>>2].z : buf[(q)>>2].w)

__global__ __launch_bounds__(64, 1) void rnn_scan_kernel(
    const float* __restrict__ X, const float* __restrict__ H0,
    const float* __restrict__ Wih, const float* __restrict__ Whh,
    const float* __restrict__ bih, const float* __restrict__ bhh,
    float* __restrict__ out)
{
  const int g = blockIdx.x * 64 + threadIdx.x;
  const int b = g >> 2;        // batch index
  const int j = g & 3;         // hidden-unit index (3 = idle lane)
  const int jr = (j < 3) ? j : 2;

  // Pre-scale weights. z_j = cc + sum_f x_f*wi_f + sum_k r_k*wh_k
  // where h = 1-2r  =>  s*sum h_k*Whh[j,k] = s*rowsum - 2s*sum r_k*Whh[j,k]
  const float wi0 = SCL * Wih[jr*3+0];
  const float wi1 = SCL * Wih[jr*3+1];
  const float wi2 = SCL * Wih[jr*3+2];
  const float a0 = Whh[jr*3+0], a1 = Whh[jr*3+1], a2 = Whh[jr*3+2];
  const float wh0 = -2.0f * SCL * a0;
  const float wh1 = -2.0f * SCL * a1;
  const float wh2 = -2.0f * SCL * a2;
  const float cc  = SCL * (bih[jr] + bhh[jr] + a0 + a1 + a2);

  // initial r from H0:  r = (1 - h)/2
  float r0 = 0.5f - 0.5f * H0[b*3+0];
  float r1 = 0.5f - 0.5f * H0[b*3+1];
  float r2 = 0.5f - 0.5f * H0[b*3+2];

  const float4* __restrict__ Xv = reinterpret_cast<const float4*>(X + (size_t)b * (TLEN*3));
  float* __restrict__ Yb = out + (size_t)b * (TLEN*3);

#define STEP(zp, O0, O1, O2) do { \
    float z_ = fmaf(r0, wh0, fmaf(r1, wh1, fmaf(r2, wh2, (zp)))); \
    float e_ = __builtin_amdgcn_exp2f(z_); \
    float rn_ = __builtin_amdgcn_rcpf(e_ + 1.0f); \
    r0 = qbcast<0>(rn_); r1 = qbcast<1>(rn_); r2 = qbcast<2>(rn_); \
    O0 = fmaf(-2.0f, r0, 1.0f); O1 = fmaf(-2.0f, r1, 1.0f); O2 = fmaf(-2.0f, r2, 1.0f); \
  } while (0)

  auto do_load = [&](float4 (&buf)[12], int ch) {
    const float4* src = Xv + ch * 12;
#pragma unroll
    for (int i = 0; i < 12; ++i) buf[i] = src[i];
  };

  auto do_chunk = [&](float4 (&buf)[12], int ch) {
#pragma unroll
    for (int g4 = 0; g4 < 4; ++g4) {
      const int f = g4 * 12;
      // input projections for the 4 steps (independent of the chain)
      float zp0 = fmaf(XC(f+0),  wi0, fmaf(XC(f+1),  wi1, fmaf(XC(f+2),  wi2, cc)));
      float zp1 = fmaf(XC(f+3),  wi0, fmaf(XC(f+4),  wi1, fmaf(XC(f+5),  wi2, cc)));
      float zp2 = fmaf(XC(f+6),  wi0, fmaf(XC(f+7),  wi1, fmaf(XC(f+8),  wi2, cc)));
      float zp3 = fmaf(XC(f+9),  wi0, fmaf(XC(f+10), wi1, fmaf(XC(f+11), wi2, cc)));
      float o[12];
      STEP(zp0, o[0], o[1],  o[2]);
      STEP(zp1, o[3], o[4],  o[5]);
      STEP(zp2, o[6], o[7],  o[8]);
      STEP(zp3, o[9], o[10], o[11]);
      if (j < 3) {
        float s0 = (j == 0) ? o[0] : (j == 1) ? o[4] : o[8];
        float s1 = (j == 0) ? o[1] : (j == 1) ? o[5] : o[9];
        float s2 = (j == 0) ? o[2] : (j == 1) ? o[6] : o[10];
        float s3 = (j == 0) ? o[3] : (j == 1) ? o[7] : o[11];
        *reinterpret_cast<float4*>(Yb + (size_t)(ch * 48 + g4 * 12 + 4 * j)) =
            make_float4(s0, s1, s2, s3);
      }
    }
  };

  // software pipeline: 64 chunks of 16 timesteps, ping-pong buffers
  float4 bufA[12], bufB[12];
  do_load(bufA, 0);
  for (int ch = 0; ch < 64; ch += 2) {
    do_load(bufB, ch + 1);
    do_chunk(bufA, ch);
    if (ch + 2 < 64) do_load(bufA, ch + 2);
    do_chunk(bufB, ch + 1);
  }

  // final hidden state h_n
  if (j < 3) {
    float rj = (j == 0) ? r0 : (j == 1) ? r1 : r2;
    out[HN_OFF + b*3 + j] = fmaf(-2.0f, rj, 1.0f);
  }
}

extern "C" void kernel_launch(void* const* d_in, const int* in_sizes, int n_in,
                              void* d_out, int out_size, void* d_ws, size_t ws_size,
                              hipStream_t stream) {
  const float* X   = (const float*)d_in[0];
  const float* H0  = (const float*)d_in[1];
  const float* Wih = (const float*)d_in[2];
  const float* Whh = (const float*)d_in[3];
  const float* bih = (const float*)d_in[4];
  const float* bhh = (const float*)d_in[5];
  float* out = (float*)d_out;

  dim3 grid(BATCH * 4 / 64), block(64);
  hipLaunchKernelGGL(rnn_scan_kernel, grid, block, 0, stream,
                     X, H0, Wih, Whh, bih, bhh, out);
}